// Round 4
// baseline (500.461 us; speedup 1.0000x reference)
//
#include <hip/hip_runtime.h>

// SparseRNN: out = COO_spmm(rows, cols, vals, inp) + bias
// N = 100000, D = 128, nnz = 6,500,000
//
// Round 12. R11 post-mortem: quarter-wave gather halved VALUBusy (53->27%)
// but dur flat at 242us, FETCH flat at 784MB -> gather is L2-FILL-PATH
// bound: 1.66GB demand, 52% L2 hit, 800MB misses at 3.3 TB/s = the wall.
// inpb (25.6MB) >> per-XCD L2 (4MB) under random column access.
// This round: COLUMN-CHUNK PHASING. Records binned by (row_local, col>>13)
// -> 13 chunks of 8192 cols = 2.1MB bf16 each (fits XCD L2). All blocks
// sweep chunks in the same order; co-resident cohorts converge on the same
// 2.1MB slice -> phase-resident L2. bin = (r>>13)&1023 (row bits || chunk
// bits, single AND). Wave keeps acc[8][8] f32 live across chunks (static
// unroll, rule #20). Sort kernel unchanged (control).
// record = val9<<23 | row_local<<17 | col (4 bytes)

#define N_FEAT      128
#define R_TILE      64
#define TILE_SHIFT  6
#define COL_MASK    0x1FFFF
#define TILE_CAP    2048       // >= n_tiles+1 (1564), pow2 for the scan
#define LSORT_CAP   12800      // edges per sort block (51.2 KB slab)
#define REC_CAP     4608       // gather staging (tile mean 4160, +6.9 sigma)
#define SORT_K      (LSORT_CAP / 512)   // 25 edges per thread
#define CH_SHIFT    13         // 8192-col chunks = 2.1MB bf16 rows
#define N_CHUNK     13         // ceil(100000 / 8192)
#define NBIN        1024       // 64 rows x 16 chunk slots

typedef unsigned int uint32;

// ---------------------------------------------------------------- f32 -> bf16
__device__ __forceinline__ unsigned short f2bf(float f) {
    unsigned int u = __float_as_uint(f);
    u = (u + 0x7FFFu + ((u >> 16) & 1u)) >> 16;   // RNE
    return (unsigned short)u;
}

// ---------------------------------------------------------------- local sort
__global__ __launch_bounds__(512)
void local_sort_kernel(const int* __restrict__ rows,
                       const int* __restrict__ cols,
                       const float* __restrict__ vals, int nnz,
                       uint32* __restrict__ records,
                       int* __restrict__ loc, int n_tiles,
                       const float* __restrict__ inp_f,
                       ushort* __restrict__ inpb, int n4) {
    __shared__ uint32 slab[LSORT_CAP];   // 51.2 KB
    __shared__ int    cnt[TILE_CAP];     // 8 KB (counts, then excl offsets)
    __shared__ int    wsum[8];

    const int b    = blockIdx.x;
    const int e0   = b * LSORT_CAP;
    const int e1   = min(e0 + LSORT_CAP, nnz);
    const int cntE = e1 - e0;
    const int tid  = threadIdx.x;
    const int lane = tid & 63, wv = tid >> 6;

    for (int i = tid; i < TILE_CAP; i += 512) cnt[i] = 0;

    // fused bf16 convert of inp (independent streaming work, hides in the
    // sort's latency bubbles)
    for (int i = b * 512 + tid; i < n4; i += gridDim.x * 512) {
        float4 f = reinterpret_cast<const float4*>(inp_f)[i];
        ushort4 h;
        h.x = f2bf(f.x); h.y = f2bf(f.y); h.z = f2bf(f.z); h.w = f2bf(f.w);
        reinterpret_cast<ushort4*>(inpb)[i] = h;
    }
    __syncthreads();

    // single pass: edges -> registers, fused histogram
    uint32 rec[SORT_K];
    int    til[SORT_K];
#pragma unroll
    for (int k = 0; k < SORT_K; ++k) {
        const int e = e0 + (k << 9) + tid;
        til[k] = -1;
        if (e < e1) {
            const int   r  = rows[e];
            const uint32 qv = __float2uint_rn(vals[e] * 511.0f) & 0x1FFu;
            rec[k] = (qv << 23) | ((uint32)(r & (R_TILE - 1)) << 17)
                   | (uint32)cols[e];
            const int t = r >> TILE_SHIFT;
            til[k] = t;
            atomicAdd(&cnt[t], 1);
        }
    }
    __syncthreads();

    // parallel exclusive scan of 2048 counts (4/thread + shuffle block-scan)
    const int g  = tid << 2;
    int c0 = cnt[g + 0], c1 = cnt[g + 1], c2 = cnt[g + 2], c3 = cnt[g + 3];
    int tsum = c0 + c1 + c2 + c3;
    int v = tsum;
    for (int off = 1; off < 64; off <<= 1) {
        int u = __shfl_up(v, off);
        if (lane >= off) v += u;
    }
    if (lane == 63) wsum[wv] = v;
    __syncthreads();
    int wpre = 0;
    for (int w = 0; w < wv; ++w) wpre += wsum[w];
    const int excl = wpre + v - tsum;
    int p0 = excl, p1 = p0 + c0, p2 = p1 + c1, p3 = p2 + c2;

    // write loc row (exclusive offsets; entry n_tiles = chunk total)
    const int rowbase = b * (n_tiles + 1);
    if (g + 3 <= n_tiles) {
        reinterpret_cast<int4*>(loc + rowbase)[tid] = make_int4(p0, p1, p2, p3);
    } else {
        if (g + 0 <= n_tiles) loc[rowbase + g + 0] = p0;
        if (g + 1 <= n_tiles) loc[rowbase + g + 1] = p1;
        if (g + 2 <= n_tiles) loc[rowbase + g + 2] = p2;
        if (g + 3 <= n_tiles) loc[rowbase + g + 3] = p3;
    }
    // each thread owns cnt[g..g+3] exclusively -> safe to overwrite in place
    cnt[g + 0] = p0; cnt[g + 1] = p1; cnt[g + 2] = p2; cnt[g + 3] = p3;
    __syncthreads();

    // place records into LDS slab straight from registers
#pragma unroll
    for (int k = 0; k < SORT_K; ++k) {
        if (til[k] >= 0) {
            const int p = atomicAdd(&cnt[til[k]], 1);
            slab[p] = rec[k];
        }
    }
    __syncthreads();

    // stream out coalesced (private slab -> no cross-block line sharing)
    uint32* outp = records + (size_t)b * LSORT_CAP;
    const int nq = cntE >> 2;
    for (int i = tid; i < nq; i += 512)
        reinterpret_cast<uint4*>(outp)[i] = reinterpret_cast<uint4*>(slab)[i];
    for (int i = (nq << 2) + tid; i < cntE; i += 512)
        outp[i] = slab[i];
}

// ---------------------------------------------------------------- gather
// one block (512 thr = 8 waves) per 64-row tile.
// quarter-wave: lane>>4 = record slot (4 records/wave instr), lane&15 =
// feature octet. Chunk-phased: bins (row_local, col_chunk), all blocks
// sweep chunks 0..12 in order; acc[8][8] lives across phases.
template <bool BF16>
__global__ __launch_bounds__(512)
void gather_kernel(const float* __restrict__ inp,
                   const ushort* __restrict__ inpb,
                   const uint32* __restrict__ records,
                   const int* __restrict__ loc,
                   int n_blocks, int n_tiles,
                   const float* __restrict__ bias,
                   float* __restrict__ out, int n_rows) {
    __shared__ uint32 raw[REC_CAP];     // 18.4 KB
    __shared__ uint32 recs[REC_CAP];    // 18.4 KB
    __shared__ int    rbeg[NBIN];       // 4 KB (bin start)
    __shared__ int    rcur[NBIN];       // 4 KB (hist -> cursor -> bin end)
    __shared__ int    wsum[8];
    __shared__ int    s_total;

    const int t    = blockIdx.x;
    const int tid  = threadIdx.x;
    const int lane = tid & 63, wv = tid >> 6;

    // zero bin counters (rcur doubles as the histogram)
    rcur[tid] = 0; rcur[tid + 512] = 0;

    // thread tid owns the segment of sort-block tid (if < n_blocks)
    int s0 = 0, len = 0;
    if (tid < n_blocks) {
        const int rb = tid * (n_tiles + 1);
        s0  = loc[rb + t];
        len = loc[rb + t + 1] - s0;
    }
    // block scan of segment lengths -> my LDS offset + total
    int v = len;
    for (int off = 1; off < 64; off <<= 1) {
        int u = __shfl_up(v, off);
        if (lane >= off) v += u;
    }
    if (lane == 63) wsum[wv] = v;
    __syncthreads();
    int wpre = 0;
    for (int w = 0; w < wv; ++w) wpre += wsum[w];
    const int myoff = wpre + v - len;
    if (tid == 511) s_total = myoff + len;
    __syncthreads();
    const int  total = s_total;
    const bool fits  = (total <= REC_CAP);

    // copy my segment into raw[], fused (row,chunk) histogram
    if (fits && len > 0) {
        const uint32* src = records + (size_t)tid * LSORT_CAP + s0;
        for (int i = 0; i < len; ++i) {
            uint32 r = src[i];
            raw[myoff + i] = r;
            atomicAdd(&rcur[(r >> CH_SHIFT) & (NBIN - 1)], 1);
        }
    }
    __syncthreads();

    // block-parallel exclusive scan of 1024 bins (2/thread)
    {
        const int g2 = tid << 1;
        int c0 = rcur[g2], c1 = rcur[g2 + 1];
        int ts = c0 + c1;
        int v2 = ts;
        for (int off = 1; off < 64; off <<= 1) {
            int u = __shfl_up(v2, off);
            if (lane >= off) v2 += u;
        }
        if (lane == 63) wsum[wv] = v2;
        __syncthreads();
        int wp = 0;
        for (int w = 0; w < wv; ++w) wp += wsum[w];
        const int ex = wp + v2 - ts;
        // exclusive ownership of bins g2,g2+1 -> safe in-place overwrite
        rbeg[g2] = ex; rbeg[g2 + 1] = ex + c0;
        rcur[g2] = ex; rcur[g2 + 1] = ex + c0;
    }
    __syncthreads();

    // permute into (row,chunk)-binned staging; after this, rcur[bin] = end
    if (fits) {
        for (int i = tid; i < total; i += blockDim.x) {
            uint32 r = raw[i];
            int p = atomicAdd(&rcur[(r >> CH_SHIFT) & (NBIN - 1)], 1);
            recs[p] = r;
        }
    }
    __syncthreads();

    const float VQ = 1.0f / 511.0f;
    const int   q  = lane >> 4;      // record slot 0..3
    const int   fq = lane & 15;      // feature octet: feats fq*8 .. fq*8+7

#define REC_ACC(k_, r_)                                                        \
    {                                                                          \
        float  vv_ = (float)((r_) >> 23) * VQ;                                 \
        size_t c_  = (size_t)((r_) & COL_MASK) << 7;                           \
        if (BF16) {                                                            \
            uint4 d_ = reinterpret_cast<const uint4*>(inpb + c_)[fq];          \
            acc[k_][0] = fmaf(vv_, __uint_as_float(d_.x << 16),         acc[k_][0]); \
            acc[k_][1] = fmaf(vv_, __uint_as_float(d_.x & 0xFFFF0000u), acc[k_][1]); \
            acc[k_][2] = fmaf(vv_, __uint_as_float(d_.y << 16),         acc[k_][2]); \
            acc[k_][3] = fmaf(vv_, __uint_as_float(d_.y & 0xFFFF0000u), acc[k_][3]); \
            acc[k_][4] = fmaf(vv_, __uint_as_float(d_.z << 16),         acc[k_][4]); \
            acc[k_][5] = fmaf(vv_, __uint_as_float(d_.z & 0xFFFF0000u), acc[k_][5]); \
            acc[k_][6] = fmaf(vv_, __uint_as_float(d_.w << 16),         acc[k_][6]); \
            acc[k_][7] = fmaf(vv_, __uint_as_float(d_.w & 0xFFFF0000u), acc[k_][7]); \
        } else {                                                               \
            const float4* rp_ = reinterpret_cast<const float4*>(inp + c_)      \
                              + (fq << 1);                                     \
            float4 A_ = rp_[0], B_ = rp_[1];                                   \
            acc[k_][0] = fmaf(vv_, A_.x, acc[k_][0]);                          \
            acc[k_][1] = fmaf(vv_, A_.y, acc[k_][1]);                          \
            acc[k_][2] = fmaf(vv_, A_.z, acc[k_][2]);                          \
            acc[k_][3] = fmaf(vv_, A_.w, acc[k_][3]);                          \
            acc[k_][4] = fmaf(vv_, B_.x, acc[k_][4]);                          \
            acc[k_][5] = fmaf(vv_, B_.y, acc[k_][5]);                          \
            acc[k_][6] = fmaf(vv_, B_.z, acc[k_][6]);                          \
            acc[k_][7] = fmaf(vv_, B_.w, acc[k_][7]);                          \
        }                                                                      \
    }

    float acc[8][8];
#pragma unroll
    for (int k = 0; k < 8; ++k)
#pragma unroll
        for (int j = 0; j < 8; ++j) acc[k][j] = 0.f;

    if (fits) {
        // chunk-phased sweep: all blocks visit chunks in the same order so
        // co-resident blocks share a 2.1MB L2-resident input slice.
        for (int c = 0; c < N_CHUNK; ++c) {
#pragma unroll
            for (int k = 0; k < 8; ++k) {
                const int bin = ((wv * 8 + k) << 4) | c;
                const int e_  = rcur[bin];
                for (int i = rbeg[bin] + q; i < e_; i += 4) {
                    uint32 r_ = recs[i];
                    REC_ACC(k, r_)
                }
            }
        }
    } else {
        // overflow fallback (statistically never): 8 passes over all
        // segments, one per owned row, k kept compile-time (rule #20)
#pragma unroll
        for (int k = 0; k < 8; ++k) {
            const int rl = wv * 8 + k;
            if (q != 0) continue;
            for (int b2 = 0; b2 < n_blocks; ++b2) {
                const int rb2 = b2 * (n_tiles + 1);
                const int q0 = loc[rb2 + t], q1 = loc[rb2 + t + 1];
                for (int i2 = q0; i2 < q1; ++i2) {
                    uint32 r_ = records[(size_t)b2 * LSORT_CAP + i2];
                    if ((int)((r_ >> 17) & (R_TILE - 1)) == rl) {
                        REC_ACC(k, r_)
                    }
                }
            }
        }
    }

    // fold quarter-group partials + writeout, one row at a time
#pragma unroll
    for (int k = 0; k < 8; ++k) {
        const int rl  = wv * 8 + k;
        const int row = (t << TILE_SHIFT) + rl;
        if (row >= n_rows) continue;

        float a0 = acc[k][0], a1 = acc[k][1], a2 = acc[k][2], a3 = acc[k][3];
        float a4 = acc[k][4], a5 = acc[k][5], a6 = acc[k][6], a7 = acc[k][7];

        a0 += __shfl_xor(a0, 16); a1 += __shfl_xor(a1, 16);
        a2 += __shfl_xor(a2, 16); a3 += __shfl_xor(a3, 16);
        a4 += __shfl_xor(a4, 16); a5 += __shfl_xor(a5, 16);
        a6 += __shfl_xor(a6, 16); a7 += __shfl_xor(a7, 16);
        a0 += __shfl_xor(a0, 32); a1 += __shfl_xor(a1, 32);
        a2 += __shfl_xor(a2, 32); a3 += __shfl_xor(a3, 32);
        a4 += __shfl_xor(a4, 32); a5 += __shfl_xor(a5, 32);
        a6 += __shfl_xor(a6, 32); a7 += __shfl_xor(a7, 32);

        if (q == 0) {
            const float b_ = bias[row];
            float4* op = reinterpret_cast<float4*>(out + (size_t)row * N_FEAT)
                       + (fq << 1);
            op[0] = make_float4(a0 + b_, a1 + b_, a2 + b_, a3 + b_);
            op[1] = make_float4(a4 + b_, a5 + b_, a6 + b_, a7 + b_);
        }
    }
#undef REC_ACC
}

// ----------------------------------------------------------------
extern "C" void kernel_launch(void* const* d_in, const int* in_sizes, int n_in,
                              void* d_out, int out_size, void* d_ws, size_t ws_size,
                              hipStream_t stream) {
    const float* inp  = (const float*)d_in[0];
    const int*   rows = (const int*)d_in[1];
    const int*   cols = (const int*)d_in[2];
    const float* vals = (const float*)d_in[3];
    const float* bias = (const float*)d_in[4];
    float*       out  = (float*)d_out;

    const int nnz      = in_sizes[1];                        // E + N
    const int n_rows   = in_sizes[4];                        // N
    const int n_inp    = in_sizes[0];                        // N * 128
    const int n_tiles  = (n_rows + R_TILE - 1) / R_TILE;     // 1563
    const int n_blocks = (nnz + LSORT_CAP - 1) / LSORT_CAP;  // 508 (<= 512)

    // workspace layout
    char*   ws  = (char*)d_ws;
    size_t  off = 0;
    uint32* records = (uint32*)(ws + off);
    off += (size_t)n_blocks * LSORT_CAP * sizeof(uint32);
    int*    loc     = (int*)(ws + off);
    off += (size_t)n_blocks * (n_tiles + 1) * sizeof(int);
    off = (off + 255) & ~(size_t)255;
    ushort* inpb    = (ushort*)(ws + off);
    const bool use_bf16 = (ws_size >= off + (size_t)n_inp * sizeof(ushort));
    const int  n4 = use_bf16 ? (n_inp / 4) : 0;

    local_sort_kernel<<<n_blocks, 512, 0, stream>>>(rows, cols, vals, nnz,
                                                    records, loc, n_tiles,
                                                    inp, inpb, n4);
    if (use_bf16)
        gather_kernel<true><<<n_tiles, 512, 0, stream>>>(inp, inpb, records, loc,
                                                         n_blocks, n_tiles, bias,
                                                         out, n_rows);
    else
        gather_kernel<false><<<n_tiles, 512, 0, stream>>>(inp, inpb, records, loc,
                                                          n_blocks, n_tiles, bias,
                                                          out, n_rows);
}

// Round 5
// 455.944 us; speedup vs baseline: 1.0976x; 1.0976x over previous
//
#include <hip/hip_runtime.h>

// SparseRNN: out = COO_spmm(rows, cols, vals, inp) + bias
// N = 100000, D = 128, nnz = 6,500,000
//
// Round 13. R12 post-mortem: chunk phasing WORKED (FETCH 784->452MB, L2 hit
// 52->76%) but dur regressed 242->336us: acc[8][8]=64 f32 can't live in the
// reported 44 arch VGPRs -> AGPR/scratch shuttle per FMA; occupancy 70->36%
// (unified-reg + 45.5KB LDS) -> halved MLP, latency-bound (hbm 1.5 TB/s).
// This round keeps the phasing, fixes the register economics:
//   HALF-WAVE records: 32 lanes x uint2 (4 bf16 feats) per input row, 2
//   records per wave-instr. All 8 rows' accumulators = acc[8][4] = 32 VGPR,
//   single chunk sweep 0..12, statically indexed (rule #20). raw[] staging
//   dropped: histogram + permute each read the (L2-warm, ~16.6KB) global
//   segment -> LDS 45.5 -> ~26.7KB, no LDS occupancy cap.
// record = val9<<23 | row_local<<17 | col (4 bytes)
// bin = (rec >> 13) & 1023  (row_local(6b) || col_chunk(4b))

#define N_FEAT      128
#define R_TILE      64
#define TILE_SHIFT  6
#define COL_MASK    0x1FFFF
#define TILE_CAP    2048       // >= n_tiles+1 (1564), pow2 for the scan
#define LSORT_CAP   12800      // edges per sort block (51.2 KB slab)
#define REC_CAP     4608       // gather staging (tile mean 4160, +6.9 sigma)
#define SORT_K      (LSORT_CAP / 512)   // 25 edges per thread
#define CH_SHIFT    13         // 8192-col chunks = 2.1MB bf16 rows
#define N_CHUNK     13         // ceil(100000 / 8192); max chunk = 12
#define NBIN        1024       // 64 rows x 16 chunk slots

typedef unsigned int uint32;

// ---------------------------------------------------------------- f32 -> bf16
__device__ __forceinline__ unsigned short f2bf(float f) {
    unsigned int u = __float_as_uint(f);
    u = (u + 0x7FFFu + ((u >> 16) & 1u)) >> 16;   // RNE
    return (unsigned short)u;
}

// ---------------------------------------------------------------- local sort
__global__ __launch_bounds__(512)
void local_sort_kernel(const int* __restrict__ rows,
                       const int* __restrict__ cols,
                       const float* __restrict__ vals, int nnz,
                       uint32* __restrict__ records,
                       int* __restrict__ loc, int n_tiles,
                       const float* __restrict__ inp_f,
                       ushort* __restrict__ inpb, int n4) {
    __shared__ uint32 slab[LSORT_CAP];   // 51.2 KB
    __shared__ int    cnt[TILE_CAP];     // 8 KB (counts, then excl offsets)
    __shared__ int    wsum[8];

    const int b    = blockIdx.x;
    const int e0   = b * LSORT_CAP;
    const int e1   = min(e0 + LSORT_CAP, nnz);
    const int cntE = e1 - e0;
    const int tid  = threadIdx.x;
    const int lane = tid & 63, wv = tid >> 6;

    for (int i = tid; i < TILE_CAP; i += 512) cnt[i] = 0;

    // fused bf16 convert of inp (independent streaming work, hides in the
    // sort's latency bubbles)
    for (int i = b * 512 + tid; i < n4; i += gridDim.x * 512) {
        float4 f = reinterpret_cast<const float4*>(inp_f)[i];
        ushort4 h;
        h.x = f2bf(f.x); h.y = f2bf(f.y); h.z = f2bf(f.z); h.w = f2bf(f.w);
        reinterpret_cast<ushort4*>(inpb)[i] = h;
    }
    __syncthreads();

    // single pass: edges -> registers, fused histogram
    uint32 rec[SORT_K];
    int    til[SORT_K];
#pragma unroll
    for (int k = 0; k < SORT_K; ++k) {
        const int e = e0 + (k << 9) + tid;
        til[k] = -1;
        if (e < e1) {
            const int   r  = rows[e];
            const uint32 qv = __float2uint_rn(vals[e] * 511.0f) & 0x1FFu;
            rec[k] = (qv << 23) | ((uint32)(r & (R_TILE - 1)) << 17)
                   | (uint32)cols[e];
            const int t = r >> TILE_SHIFT;
            til[k] = t;
            atomicAdd(&cnt[t], 1);
        }
    }
    __syncthreads();

    // parallel exclusive scan of 2048 counts (4/thread + shuffle block-scan)
    const int g  = tid << 2;
    int c0 = cnt[g + 0], c1 = cnt[g + 1], c2 = cnt[g + 2], c3 = cnt[g + 3];
    int tsum = c0 + c1 + c2 + c3;
    int v = tsum;
    for (int off = 1; off < 64; off <<= 1) {
        int u = __shfl_up(v, off);
        if (lane >= off) v += u;
    }
    if (lane == 63) wsum[wv] = v;
    __syncthreads();
    int wpre = 0;
    for (int w = 0; w < wv; ++w) wpre += wsum[w];
    const int excl = wpre + v - tsum;
    int p0 = excl, p1 = p0 + c0, p2 = p1 + c1, p3 = p2 + c2;

    // write loc row (exclusive offsets; entry n_tiles = chunk total)
    const int rowbase = b * (n_tiles + 1);
    if (g + 3 <= n_tiles) {
        reinterpret_cast<int4*>(loc + rowbase)[tid] = make_int4(p0, p1, p2, p3);
    } else {
        if (g + 0 <= n_tiles) loc[rowbase + g + 0] = p0;
        if (g + 1 <= n_tiles) loc[rowbase + g + 1] = p1;
        if (g + 2 <= n_tiles) loc[rowbase + g + 2] = p2;
        if (g + 3 <= n_tiles) loc[rowbase + g + 3] = p3;
    }
    // each thread owns cnt[g..g+3] exclusively -> safe to overwrite in place
    cnt[g + 0] = p0; cnt[g + 1] = p1; cnt[g + 2] = p2; cnt[g + 3] = p3;
    __syncthreads();

    // place records into LDS slab straight from registers
#pragma unroll
    for (int k = 0; k < SORT_K; ++k) {
        if (til[k] >= 0) {
            const int p = atomicAdd(&cnt[til[k]], 1);
            slab[p] = rec[k];
        }
    }
    __syncthreads();

    // stream out coalesced (private slab -> no cross-block line sharing)
    uint32* outp = records + (size_t)b * LSORT_CAP;
    const int nq = cntE >> 2;
    for (int i = tid; i < nq; i += 512)
        reinterpret_cast<uint4*>(outp)[i] = reinterpret_cast<uint4*>(slab)[i];
    for (int i = (nq << 2) + tid; i < cntE; i += 512)
        outp[i] = slab[i];
}

// ---------------------------------------------------------------- gather
// one block (512 thr = 8 waves) per 64-row tile.
// half-wave: lane>>5 = record slot (2 records/wave instr), lane&31 =
// feature quad (32 lanes x 8B = one 256B bf16 row, or x16B f32 row).
// Chunk-phased: bins (row_local, col_chunk), all blocks sweep chunks
// 0..12 in the same order; acc[8][4] (32 VGPR) lives across phases.
template <bool BF16>
__global__ __launch_bounds__(512)
void gather_kernel(const float* __restrict__ inp,
                   const ushort* __restrict__ inpb,
                   const uint32* __restrict__ records,
                   const int* __restrict__ loc,
                   int n_blocks, int n_tiles,
                   const float* __restrict__ bias,
                   float* __restrict__ out, int n_rows) {
    __shared__ uint32 recs[REC_CAP];    // 18.4 KB
    __shared__ int    rbeg[NBIN];       // 4 KB (bin start)
    __shared__ int    rcur[NBIN];       // 4 KB (hist -> cursor -> bin end)
    __shared__ int    wsum[8];
    __shared__ int    s_total;

    const int t    = blockIdx.x;
    const int tid  = threadIdx.x;
    const int lane = tid & 63, wv = tid >> 6;

    // zero bin histogram
    rcur[tid] = 0; rcur[tid + 512] = 0;

    // thread tid owns the segment of sort-block tid (if < n_blocks)
    int s0 = 0, len = 0;
    if (tid < n_blocks) {
        const int rb = tid * (n_tiles + 1);
        s0  = loc[rb + t];
        len = loc[rb + t + 1] - s0;
    }
    // block scan of segment lengths -> total record count
    int v = len;
    for (int off = 1; off < 64; off <<= 1) {
        int u = __shfl_up(v, off);
        if (lane >= off) v += u;
    }
    if (lane == 63) wsum[wv] = v;
    __syncthreads();
    int wpre = 0;
    for (int w = 0; w < wv; ++w) wpre += wsum[w];
    if (tid == 511) s_total = wpre + v;
    __syncthreads();
    const int  total = s_total;
    const bool fits  = (total <= REC_CAP);

    const uint32* src = records + (size_t)tid * LSORT_CAP + s0;

    // pass A: (row,chunk) histogram from the global segment
    if (fits && len > 0) {
        for (int i = 0; i < len; ++i)
            atomicAdd(&rcur[(src[i] >> CH_SHIFT) & (NBIN - 1)], 1);
    }
    __syncthreads();

    // block-parallel exclusive scan of 1024 bins (2/thread)
    {
        const int g2 = tid << 1;
        int c0 = rcur[g2], c1 = rcur[g2 + 1];
        int ts = c0 + c1;
        int v2 = ts;
        for (int off = 1; off < 64; off <<= 1) {
            int u = __shfl_up(v2, off);
            if (lane >= off) v2 += u;
        }
        if (lane == 63) wsum[wv] = v2;
        __syncthreads();
        int wp = 0;
        for (int w = 0; w < wv; ++w) wp += wsum[w];
        const int ex = wp + v2 - ts;
        // exclusive ownership of bins g2,g2+1 -> safe in-place overwrite
        rbeg[g2] = ex; rbeg[g2 + 1] = ex + c0;
        rcur[g2] = ex; rcur[g2 + 1] = ex + c0;
    }
    __syncthreads();

    // pass B: permute records into binned staging (segment is L2-warm);
    // after this, rcur[bin] = bin end
    if (fits && len > 0) {
        for (int i = 0; i < len; ++i) {
            uint32 r = src[i];
            int p = atomicAdd(&rcur[(r >> CH_SHIFT) & (NBIN - 1)], 1);
            recs[p] = r;
        }
    }
    __syncthreads();

    const float VQ   = 1.0f / 511.0f;
    const int   slot = lane >> 5;    // record slot 0..1
    const int   fh   = lane & 31;    // feature quad: feats fh*4 .. fh*4+3

    float acc[8][4];
#pragma unroll
    for (int k = 0; k < 8; ++k)
#pragma unroll
        for (int j = 0; j < 4; ++j) acc[k][j] = 0.f;

#define REC_ACC(k_, r_)                                                        \
    {                                                                          \
        const float  vv_ = (float)((r_) >> 23) * VQ;                           \
        const size_t c_  = (size_t)((r_) & COL_MASK) << 7;                     \
        if (BF16) {                                                            \
            uint2 d_ = reinterpret_cast<const uint2*>(inpb + c_)[fh];          \
            acc[k_][0] = fmaf(vv_, __uint_as_float(d_.x << 16),         acc[k_][0]); \
            acc[k_][1] = fmaf(vv_, __uint_as_float(d_.x & 0xFFFF0000u), acc[k_][1]); \
            acc[k_][2] = fmaf(vv_, __uint_as_float(d_.y << 16),         acc[k_][2]); \
            acc[k_][3] = fmaf(vv_, __uint_as_float(d_.y & 0xFFFF0000u), acc[k_][3]); \
        } else {                                                               \
            float4 A_ = reinterpret_cast<const float4*>(inp + c_)[fh];         \
            acc[k_][0] = fmaf(vv_, A_.x, acc[k_][0]);                          \
            acc[k_][1] = fmaf(vv_, A_.y, acc[k_][1]);                          \
            acc[k_][2] = fmaf(vv_, A_.z, acc[k_][2]);                          \
            acc[k_][3] = fmaf(vv_, A_.w, acc[k_][3]);                          \
        }                                                                      \
    }

    if (fits) {
        // chunk-phased sweep: all blocks visit chunks in the same order so
        // co-resident blocks share a 2.1MB L2-resident input slice.
        for (int c = 0; c < N_CHUNK; ++c) {
#pragma unroll
            for (int k = 0; k < 8; ++k) {
                const int bin = ((wv * 8 + k) << 4) | c;
                const int e_  = rcur[bin];
                for (int i = rbeg[bin] + slot; i < e_; i += 2) {
                    const uint32 r_ = recs[i];
                    REC_ACC(k, r_)
                }
            }
        }
    } else {
        // overflow fallback (statistically never): walk all segments,
        // one pass per owned row, k compile-time (rule #20)
#pragma unroll
        for (int k = 0; k < 8; ++k) {
            const int rl = wv * 8 + k;
            for (int b2 = 0; b2 < n_blocks; ++b2) {
                const int rb2 = b2 * (n_tiles + 1);
                const int q0 = loc[rb2 + t], q1 = loc[rb2 + t + 1];
                for (int i2 = q0; i2 < q1; ++i2) {
                    uint32 r_ = records[(size_t)b2 * LSORT_CAP + i2];
                    if ((int)((r_ >> 17) & (R_TILE - 1)) == rl && slot == 0) {
                        REC_ACC(k, r_)
                    }
                }
            }
        }
    }

    // fold slot partials + writeout (32 lanes x float4 = full 512B f32 row)
#pragma unroll
    for (int k = 0; k < 8; ++k) {
        const int row = (t << TILE_SHIFT) + wv * 8 + k;
        if (row >= n_rows) continue;

        float a0 = acc[k][0], a1 = acc[k][1], a2 = acc[k][2], a3 = acc[k][3];
        a0 += __shfl_xor(a0, 32); a1 += __shfl_xor(a1, 32);
        a2 += __shfl_xor(a2, 32); a3 += __shfl_xor(a3, 32);

        if (slot == 0) {
            const float b_ = bias[row];
            float4* op = reinterpret_cast<float4*>(out + (size_t)row * N_FEAT);
            op[fh] = make_float4(a0 + b_, a1 + b_, a2 + b_, a3 + b_);
        }
    }
#undef REC_ACC
}

// ----------------------------------------------------------------
extern "C" void kernel_launch(void* const* d_in, const int* in_sizes, int n_in,
                              void* d_out, int out_size, void* d_ws, size_t ws_size,
                              hipStream_t stream) {
    const float* inp  = (const float*)d_in[0];
    const int*   rows = (const int*)d_in[1];
    const int*   cols = (const int*)d_in[2];
    const float* vals = (const float*)d_in[3];
    const float* bias = (const float*)d_in[4];
    float*       out  = (float*)d_out;

    const int nnz      = in_sizes[1];                        // E + N
    const int n_rows   = in_sizes[4];                        // N
    const int n_inp    = in_sizes[0];                        // N * 128
    const int n_tiles  = (n_rows + R_TILE - 1) / R_TILE;     // 1563
    const int n_blocks = (nnz + LSORT_CAP - 1) / LSORT_CAP;  // 508 (<= 512)

    // workspace layout
    char*   ws  = (char*)d_ws;
    size_t  off = 0;
    uint32* records = (uint32*)(ws + off);
    off += (size_t)n_blocks * LSORT_CAP * sizeof(uint32);
    int*    loc     = (int*)(ws + off);
    off += (size_t)n_blocks * (n_tiles + 1) * sizeof(int);
    off = (off + 255) & ~(size_t)255;
    ushort* inpb    = (ushort*)(ws + off);
    const bool use_bf16 = (ws_size >= off + (size_t)n_inp * sizeof(ushort));
    const int  n4 = use_bf16 ? (n_inp / 4) : 0;

    local_sort_kernel<<<n_blocks, 512, 0, stream>>>(rows, cols, vals, nnz,
                                                    records, loc, n_tiles,
                                                    inp, inpb, n4);
    if (use_bf16)
        gather_kernel<true><<<n_tiles, 512, 0, stream>>>(inp, inpb, records, loc,
                                                         n_blocks, n_tiles, bias,
                                                         out, n_rows);
    else
        gather_kernel<false><<<n_tiles, 512, 0, stream>>>(inp, inpb, records, loc,
                                                          n_blocks, n_tiles, bias,
                                                          out, n_rows);
}

// Round 6
// 407.638 us; speedup vs baseline: 1.2277x; 1.1185x over previous
//
#include <hip/hip_runtime.h>

// SparseRNN: out = COO_spmm(rows, cols, vals, inp) + bias
// N = 100000, D = 128, nnz = 6,500,000
//
// Round 14. R12/R13 post-mortem: chunk phasing cut FETCH 784->395MB but
// gather got SLOWER (242->292/336), and R11/R13's L3-warm dispatches
// (FETCH~0) run at the SAME duration as cold -> gather is bound by the
// CU<->L2/L3 request path at ~6.9 TB/s demand (1.66GB / 242us), NOT by
// HBM fill. Locality phasing cannot help; it only broke R11's long
// pipelined row loops. Revert gather to the exact R11 structure (best
// measured: 242us).
// This round's single experiment: the sort chain (165us vs ~30us BW floor).
//   - paired edge loads: int2/int2/float2 (39 x 8B loads/thread vs 78 x 4B)
//     -> LSORT_CAP 13312 (mult of 1024, 489 blocks <= 512, LDS 61.3KB)
//   - bf16 cvt moved to the END of sort: it's independent work that was
//     barrier-serialized BEFORE the edge loads; at the end it overlaps the
//     scan/placement/streamout phases.
// record = val9<<23 | row_local<<17 | col (4 bytes)

#define N_FEAT      128
#define R_TILE      64
#define TILE_SHIFT  6
#define COL_MASK    0x1FFFF
#define TILE_CAP    2048       // >= n_tiles+1 (1564), pow2 for the scan
#define LSORT_CAP   13312      // edges per sort block (53.2 KB slab, 489 blk)
#define REC_CAP     4608       // gather staging (tile mean 4160, +6.9 sigma)
#define SORT_K      (LSORT_CAP / 512)   // 26 edges per thread
#define SORT_P      (SORT_K / 2)        // 13 edge PAIRS per thread

typedef unsigned int uint32;

// ---------------------------------------------------------------- f32 -> bf16
__device__ __forceinline__ unsigned short f2bf(float f) {
    unsigned int u = __float_as_uint(f);
    u = (u + 0x7FFFu + ((u >> 16) & 1u)) >> 16;   // RNE
    return (unsigned short)u;
}

__device__ __forceinline__ uint32 pack_rec(int r, int c, float v) {
    const uint32 qv = __float2uint_rn(v * 511.0f) & 0x1FFu;
    return (qv << 23) | ((uint32)(r & (R_TILE - 1)) << 17) | (uint32)c;
}

// ---------------------------------------------------------------- local sort
__global__ __launch_bounds__(512)
void local_sort_kernel(const int* __restrict__ rows,
                       const int* __restrict__ cols,
                       const float* __restrict__ vals, int nnz,
                       uint32* __restrict__ records,
                       int* __restrict__ loc, int n_tiles,
                       const float* __restrict__ inp_f,
                       ushort* __restrict__ inpb, int n4) {
    __shared__ uint32 slab[LSORT_CAP];   // 53.2 KB
    __shared__ int    cnt[TILE_CAP];     // 8 KB (counts, then excl offsets)
    __shared__ int    wsum[8];

    const int b    = blockIdx.x;
    const int e0   = b * LSORT_CAP;
    const int e1   = min(e0 + LSORT_CAP, nnz);
    const int cntE = e1 - e0;
    const int tid  = threadIdx.x;
    const int lane = tid & 63, wv = tid >> 6;

    for (int i = tid; i < TILE_CAP; i += 512) cnt[i] = 0;
    __syncthreads();

    // single pass: edge PAIRS -> registers, fused histogram.
    // thread owns edges (e0 + k*1024 + 2*tid, +1): int2/int2/float2 loads.
    uint32 rec[SORT_K];
    int    til[SORT_K];
#pragma unroll
    for (int k = 0; k < SORT_P; ++k) {
        const int e  = e0 + (k << 10) + (tid << 1);
        const int i0 = k << 1, i1 = i0 + 1;
        til[i0] = -1; til[i1] = -1;
        if (e + 1 < e1) {
            const int2   r2 = *reinterpret_cast<const int2*>(rows + e);
            const int2   c2 = *reinterpret_cast<const int2*>(cols + e);
            const float2 v2 = *reinterpret_cast<const float2*>(vals + e);
            rec[i0] = pack_rec(r2.x, c2.x, v2.x);
            rec[i1] = pack_rec(r2.y, c2.y, v2.y);
            til[i0] = r2.x >> TILE_SHIFT;
            til[i1] = r2.y >> TILE_SHIFT;
            atomicAdd(&cnt[til[i0]], 1);
            atomicAdd(&cnt[til[i1]], 1);
        } else if (e < e1) {
            const int   r = rows[e];
            rec[i0] = pack_rec(r, cols[e], vals[e]);
            til[i0] = r >> TILE_SHIFT;
            atomicAdd(&cnt[til[i0]], 1);
        }
    }
    __syncthreads();

    // parallel exclusive scan of 2048 counts (4/thread + shuffle block-scan)
    const int g  = tid << 2;
    int c0 = cnt[g + 0], c1 = cnt[g + 1], c2 = cnt[g + 2], c3 = cnt[g + 3];
    int tsum = c0 + c1 + c2 + c3;
    int v = tsum;
    for (int off = 1; off < 64; off <<= 1) {
        int u = __shfl_up(v, off);
        if (lane >= off) v += u;
    }
    if (lane == 63) wsum[wv] = v;
    __syncthreads();
    int wpre = 0;
    for (int w = 0; w < wv; ++w) wpre += wsum[w];
    const int excl = wpre + v - tsum;
    int p0 = excl, p1 = p0 + c0, p2 = p1 + c1, p3 = p2 + c2;

    // write loc row (exclusive offsets; entry n_tiles = chunk total)
    const int rowbase = b * (n_tiles + 1);
    if (g + 3 <= n_tiles) {
        reinterpret_cast<int4*>(loc + rowbase)[tid] = make_int4(p0, p1, p2, p3);
    } else {
        if (g + 0 <= n_tiles) loc[rowbase + g + 0] = p0;
        if (g + 1 <= n_tiles) loc[rowbase + g + 1] = p1;
        if (g + 2 <= n_tiles) loc[rowbase + g + 2] = p2;
        if (g + 3 <= n_tiles) loc[rowbase + g + 3] = p3;
    }
    // each thread owns cnt[g..g+3] exclusively -> safe to overwrite in place
    cnt[g + 0] = p0; cnt[g + 1] = p1; cnt[g + 2] = p2; cnt[g + 3] = p3;
    __syncthreads();

    // place records into LDS slab straight from registers
#pragma unroll
    for (int k = 0; k < SORT_K; ++k) {
        if (til[k] >= 0) {
            const int p = atomicAdd(&cnt[til[k]], 1);
            slab[p] = rec[k];
        }
    }
    __syncthreads();

    // stream out coalesced (private slab -> no cross-block line sharing)
    uint32* outp = records + (size_t)b * LSORT_CAP;
    const int nq = cntE >> 2;
    for (int i = tid; i < nq; i += 512)
        reinterpret_cast<uint4*>(outp)[i] = reinterpret_cast<uint4*>(slab)[i];
    for (int i = (nq << 2) + tid; i < cntE; i += 512)
        outp[i] = slab[i];

    // fused bf16 convert of inp, at the END: independent streaming work that
    // overlaps other waves'/blocks' scan, placement, and streamout phases
    // instead of delaying the edge-load critical chain.
    for (int i = b * 512 + tid; i < n4; i += gridDim.x * 512) {
        float4 f = reinterpret_cast<const float4*>(inp_f)[i];
        ushort4 h;
        h.x = f2bf(f.x); h.y = f2bf(f.y); h.z = f2bf(f.z); h.w = f2bf(f.w);
        reinterpret_cast<ushort4*>(inpb)[i] = h;
    }
}

// ---------------------------------------------------------------- gather
// one block (512 thr = 8 waves) per 64-row tile.  (R11 structure, verbatim:
// measured 242us / FETCH 784MB / VALU 27% / occ 70%; warm-L3 run identical
// -> request-path bound, locality tricks don't apply.)
// quarter-wave scheme: lane>>4 = record slot (4 records per wave instr),
// lane&15 = feature octet (16 lanes x 16B = one 256B bf16 row).
template <bool BF16>
__global__ __launch_bounds__(512)
void gather_kernel(const float* __restrict__ inp,
                   const ushort* __restrict__ inpb,
                   const uint32* __restrict__ records,
                   const int* __restrict__ loc,
                   int n_blocks, int n_tiles,
                   const float* __restrict__ bias,
                   float* __restrict__ out, int n_rows) {
    __shared__ uint32 raw[REC_CAP];     // 18.4 KB
    __shared__ uint32 recs[REC_CAP];    // 18.4 KB
    __shared__ int    rcnt[R_TILE];
    __shared__ int    rbeg[R_TILE + 1];
    __shared__ int    rcur[R_TILE];
    __shared__ int    wsum[8];
    __shared__ int    s_total;

    const int t    = blockIdx.x;
    const int tid  = threadIdx.x;
    const int lane = tid & 63, wv = tid >> 6;

    if (tid < R_TILE) rcnt[tid] = 0;

    // thread tid owns the segment of sort-block tid (if < n_blocks)
    int s0 = 0, len = 0;
    if (tid < n_blocks) {
        const int rb = tid * (n_tiles + 1);
        s0  = loc[rb + t];
        len = loc[rb + t + 1] - s0;
    }
    // block scan of segment lengths -> my LDS offset + total
    int v = len;
    for (int off = 1; off < 64; off <<= 1) {
        int u = __shfl_up(v, off);
        if (lane >= off) v += u;
    }
    if (lane == 63) wsum[wv] = v;
    __syncthreads();
    int wpre = 0;
    for (int w = 0; w < wv; ++w) wpre += wsum[w];
    const int myoff = wpre + v - len;
    if (tid == 511) s_total = myoff + len;
    __syncthreads();
    const int  total = s_total;
    const bool fits  = (total <= REC_CAP);

    // copy my segment into raw[], fused row histogram
    if (fits && len > 0) {
        const uint32* src = records + (size_t)tid * LSORT_CAP + s0;
        for (int i = 0; i < len; ++i) {
            uint32 r = src[i];
            raw[myoff + i] = r;
            atomicAdd(&rcnt[(r >> 17) & (R_TILE - 1)], 1);
        }
    }
    __syncthreads();

    // wave-parallel exclusive scan of the 64 row counts (wave 0)
    if (wv == 0) {
        int c = rcnt[lane];
        int s = c;
        for (int off = 1; off < 64; off <<= 1) {
            int u = __shfl_up(s, off);
            if (lane >= off) s += u;
        }
        rbeg[lane] = s - c;
        rcur[lane] = s - c;
        if (lane == 63) rbeg[R_TILE] = s;
    }
    __syncthreads();

    // permute into row-grouped staging
    if (fits) {
        for (int i = tid; i < total; i += blockDim.x) {
            uint32 r = raw[i];
            int p = atomicAdd(&rcur[(r >> 17) & (R_TILE - 1)], 1);
            recs[p] = r;
        }
    }
    __syncthreads();

    const float VQ = 1.0f / 511.0f;
    const int   q  = lane >> 4;      // record slot 0..3
    const int   fq = lane & 15;      // feature octet: feats fq*8 .. fq*8+7

#define REC_ACC(r_)                                                            \
    {                                                                          \
        float  vv_ = (float)((r_) >> 23) * VQ;                                 \
        size_t c_  = (size_t)((r_) & COL_MASK) << 7;                           \
        if (BF16) {                                                            \
            uint4 d_ = reinterpret_cast<const uint4*>(inpb + c_)[fq];          \
            a0 = fmaf(vv_, __uint_as_float(d_.x << 16),         a0);           \
            a1 = fmaf(vv_, __uint_as_float(d_.x & 0xFFFF0000u), a1);           \
            a2 = fmaf(vv_, __uint_as_float(d_.y << 16),         a2);           \
            a3 = fmaf(vv_, __uint_as_float(d_.y & 0xFFFF0000u), a3);           \
            a4 = fmaf(vv_, __uint_as_float(d_.z << 16),         a4);           \
            a5 = fmaf(vv_, __uint_as_float(d_.z & 0xFFFF0000u), a5);           \
            a6 = fmaf(vv_, __uint_as_float(d_.w << 16),         a6);           \
            a7 = fmaf(vv_, __uint_as_float(d_.w & 0xFFFF0000u), a7);           \
        } else {                                                               \
            const float4* rp_ = reinterpret_cast<const float4*>(inp + c_)      \
                              + (fq << 1);                                     \
            float4 A_ = rp_[0], B_ = rp_[1];                                   \
            a0 = fmaf(vv_, A_.x, a0); a1 = fmaf(vv_, A_.y, a1);                \
            a2 = fmaf(vv_, A_.z, a2); a3 = fmaf(vv_, A_.w, a3);                \
            a4 = fmaf(vv_, B_.x, a4); a5 = fmaf(vv_, B_.y, a5);                \
            a6 = fmaf(vv_, B_.z, a6); a7 = fmaf(vv_, B_.w, a7);                \
        }                                                                      \
    }

    for (int k = 0; k < 8; ++k) {
        const int rl  = wv * 8 + k;       // 8 waves x 8 rows = 64
        const int row = (t << TILE_SHIFT) + rl;
        if (row >= n_rows) break;

        float a0 = 0.f, a1 = 0.f, a2 = 0.f, a3 = 0.f;
        float a4 = 0.f, a5 = 0.f, a6 = 0.f, a7 = 0.f;

        if (fits) {
            const int s = rbeg[rl], e_ = rbeg[rl + 1];
            int i = s;
            // 16 records / iter = 4 independent dwordx4 loads in flight
            for (; i + 15 < e_; i += 16) {
                { uint32 r_ = recs[i +  0 + q]; REC_ACC(r_) }
                { uint32 r_ = recs[i +  4 + q]; REC_ACC(r_) }
                { uint32 r_ = recs[i +  8 + q]; REC_ACC(r_) }
                { uint32 r_ = recs[i + 12 + q]; REC_ACC(r_) }
            }
            for (; i < e_; i += 4) {
                const int ii_ = i + q;
                if (ii_ < e_) { uint32 r_ = recs[ii_]; REC_ACC(r_) }
            }
        } else {
            // overflow fallback (statistically never): walk all segments
            for (int b2 = 0; b2 < n_blocks; ++b2) {
                const int rb2 = b2 * (n_tiles + 1);
                const int q0 = loc[rb2 + t], q1 = loc[rb2 + t + 1];
                for (int i2 = q0; i2 < q1; ++i2) {
                    uint32 r_ = records[(size_t)b2 * LSORT_CAP + i2];
                    if ((int)((r_ >> 17) & (R_TILE - 1)) == rl && q == 0) {
                        REC_ACC(r_)
                    }
                }
            }
        }

        // fold the 4 quarter-group partials (butterfly over bits 4,5)
        a0 += __shfl_xor(a0, 16); a1 += __shfl_xor(a1, 16);
        a2 += __shfl_xor(a2, 16); a3 += __shfl_xor(a3, 16);
        a4 += __shfl_xor(a4, 16); a5 += __shfl_xor(a5, 16);
        a6 += __shfl_xor(a6, 16); a7 += __shfl_xor(a7, 16);
        a0 += __shfl_xor(a0, 32); a1 += __shfl_xor(a1, 32);
        a2 += __shfl_xor(a2, 32); a3 += __shfl_xor(a3, 32);
        a4 += __shfl_xor(a4, 32); a5 += __shfl_xor(a5, 32);
        a6 += __shfl_xor(a6, 32); a7 += __shfl_xor(a7, 32);

        if (q == 0) {
            const float b_ = bias[row];
            float4* op = reinterpret_cast<float4*>(out + (size_t)row * N_FEAT)
                       + (fq << 1);
            op[0] = make_float4(a0 + b_, a1 + b_, a2 + b_, a3 + b_);
            op[1] = make_float4(a4 + b_, a5 + b_, a6 + b_, a7 + b_);
        }
    }
#undef REC_ACC
}

// ----------------------------------------------------------------
extern "C" void kernel_launch(void* const* d_in, const int* in_sizes, int n_in,
                              void* d_out, int out_size, void* d_ws, size_t ws_size,
                              hipStream_t stream) {
    const float* inp  = (const float*)d_in[0];
    const int*   rows = (const int*)d_in[1];
    const int*   cols = (const int*)d_in[2];
    const float* vals = (const float*)d_in[3];
    const float* bias = (const float*)d_in[4];
    float*       out  = (float*)d_out;

    const int nnz      = in_sizes[1];                        // E + N
    const int n_rows   = in_sizes[4];                        // N
    const int n_inp    = in_sizes[0];                        // N * 128
    const int n_tiles  = (n_rows + R_TILE - 1) / R_TILE;     // 1563
    const int n_blocks = (nnz + LSORT_CAP - 1) / LSORT_CAP;  // 489 (<= 512)

    // workspace layout
    char*   ws  = (char*)d_ws;
    size_t  off = 0;
    uint32* records = (uint32*)(ws + off);
    off += (size_t)n_blocks * LSORT_CAP * sizeof(uint32);
    int*    loc     = (int*)(ws + off);
    off += (size_t)n_blocks * (n_tiles + 1) * sizeof(int);
    off = (off + 255) & ~(size_t)255;
    ushort* inpb    = (ushort*)(ws + off);
    const bool use_bf16 = (ws_size >= off + (size_t)n_inp * sizeof(ushort));
    const int  n4 = use_bf16 ? (n_inp / 4) : 0;

    local_sort_kernel<<<n_blocks, 512, 0, stream>>>(rows, cols, vals, nnz,
                                                    records, loc, n_tiles,
                                                    inp, inpb, n4);
    if (use_bf16)
        gather_kernel<true><<<n_tiles, 512, 0, stream>>>(inp, inpb, records, loc,
                                                         n_blocks, n_tiles, bias,
                                                         out, n_rows);
    else
        gather_kernel<false><<<n_tiles, 512, 0, stream>>>(inp, inpb, records, loc,
                                                          n_blocks, n_tiles, bias,
                                                          out, n_rows);
}